// Round 8
// baseline (321.863 us; speedup 1.0000x reference)
//
#include <hip/hip_runtime.h>

#define NG 16384
#define NT 200
#define FREEZE_EPS 3e-4f

// DPP cross-lane (VALU pipe), all within aligned 8-lane octets
#define DPPF(v, ctrl) __int_as_float(__builtin_amdgcn_update_dpp( \
    0, __float_as_int(v), (ctrl), 0xF, 0xF, true))
#define QP1(v) DPPF(v, 0xB1)   // src lane ^ 1
#define QP2(v) DPPF(v, 0x4E)   // src lane ^ 2
#define RHM(v) DPPF(v, 0x141)  // src lane ^ 7 (row_half_mirror)
// LDS-pipe broadcast from absolute octet lane (addr precomputed)
#define BPERM(v, a) __int_as_float(__builtin_amdgcn_ds_bpermute((a), __float_as_int(v)))

__device__ __forceinline__ float allred8(float v) {
  v += QP1(v); v += QP2(v); v += RHM(v); return v;
}
// reduce-scatter butterfly: lane r ends with sum_k F[r][k]*val[k].
// Fd[s] = F[r^kd[s]][r], kd = [0,1,2,3,7,6,5,4].
__device__ __forceinline__ float matvec8(const float* __restrict__ Fd, float val) {
  float c0 = Fd[0]*val, c1 = Fd[1]*val, c2 = Fd[2]*val, c3 = Fd[3]*val;
  float c4 = Fd[4]*val, c5 = Fd[5]*val, c6 = Fd[6]*val, c7 = Fd[7]*val;
  float a0 = c0 + RHM(c4), a1 = c1 + RHM(c5), a2 = c2 + RHM(c6), a3 = c3 + RHM(c7);
  float b0 = a0 + QP2(a2), b1 = a1 + QP2(a3);
  return b0 + QP1(b1);
}

__global__ __launch_bounds__(256, 1)
void kf_kernel(const float* __restrict__ x,
               const float* __restrict__ m0,
               const float* __restrict__ P0,
               const float* __restrict__ Fm,
               const float* __restrict__ Qm,
               const float* __restrict__ Hm,
               const float* __restrict__ Rm,
               float* __restrict__ out) {
  const int tid  = threadIdx.x;
  const int lane = tid & 63;
  const int r    = tid & 7;
  const int g    = blockIdx.x * 32 + (tid >> 3);

  // ---- wave-uniform parameters (compiler scalarizes -> SGPR) ----
  float Fs[64];
#pragma unroll
  for (int i = 0; i < 64; ++i) Fs[i] = Fm[i];
  float Hs0[8], Hs1[8];
#pragma unroll
  for (int i = 0; i < 8; ++i) { Hs0[i] = Hm[i]; Hs1[i] = Hm[8 + i]; }
  const float R00 = Rm[0], R01 = Rm[1], R11 = Rm[3];

  // ---- per-lane tables ----
  constexpr int kD[8] = {0, 1, 2, 3, 7, 6, 5, 4};
  float Fd[8];    // F[r^kd[s]][r]  (matvec8)
#pragma unroll
  for (int s = 0; s < 8; ++s) Fd[s] = Fm[((r ^ kD[s]) << 3) | r];
  float Frow[8], Qrow[8], Fcol[8];
#pragma unroll
  for (int k = 0; k < 8; ++k) {
    Frow[k] = Fm[(r << 3) | k];   // F[r][k]
    Qrow[k] = Qm[(r << 3) | k];   // Q[r][k]
    Fcol[k] = Fm[(k << 3) | r];   // F[k][r]
  }
  const float Hr0 = Hm[r], Hr1 = Hm[8 + r];

  int bp[8];  // bpermute byte-addresses for absolute octet lane k
#pragma unroll
  for (int k = 0; k < 8; ++k) bp[k] = (((lane & 56) | k) << 2);

  // ---- per-group state: lane r holds m[r] and P[r][0..7] (absolute) ----
  float m = m0[(size_t)g * 8 + r];
  float P[8];
  {
    const float4* p0v = reinterpret_cast<const float4*>(P0 + (size_t)g * 64 + r * 8);
    float4 a = p0v[0], b = p0v[1];
    P[0] = a.x; P[1] = a.y; P[2] = a.z; P[3] = a.w;
    P[4] = b.x; P[5] = b.y; P[6] = b.z; P[7] = b.w;
  }

  const float* xg = x + (size_t)g * NT * 2;
  float* mo = out + (size_t)g * NT * 2;
  float* co = out + (size_t)NG * NT * 2 + (size_t)g * NT * 4;

  float kt0 = 0.f, kt1 = 0.f, s00 = 0.f, s01 = 0.f, s11 = 0.f;

  // ---- x double-buffer: 4-step batches ----
  float4 xa = *reinterpret_cast<const float4*>(xg);
  float4 xb = *reinterpret_cast<const float4*>(xg + 4);
  float4 na = *reinterpret_cast<const float4*>(xg + 8);
  float4 nb = *reinterpret_cast<const float4*>(xg + 12);

  int tb = 0;
  bool wfrozen = false;

  // ================= Phase 1: Riccati (until wave-uniform freeze) ==========
#pragma unroll 1
  for (; tb < NT && !wfrozen; tb += 4) {
    bool fz = false;
#pragma unroll
    for (int j = 0; j < 4; ++j) {
      const int t = tb + j;
      const float x0 = (j == 0) ? xa.x : (j == 1) ? xa.z : (j == 2) ? xb.x : xb.z;
      const float x1 = (j == 0) ? xa.y : (j == 1) ? xa.w : (j == 2) ? xb.y : xb.w;

      // ---- measurement mean mm = H m (DPP allreduce) ----
      float mm0 = allred8(Hr0 * m);
      float mm1 = allred8(Hr1 * m);

      // ---- hp_m = (H P)[m][r], SGPR coefficients, tree-summed ----
      float a0 = fmaf(Hs0[1], P[1], Hs0[0] * P[0]);
      float a1 = fmaf(Hs0[3], P[3], Hs0[2] * P[2]);
      float a2 = fmaf(Hs0[5], P[5], Hs0[4] * P[4]);
      float a3 = fmaf(Hs0[7], P[7], Hs0[6] * P[6]);
      const float hp0 = (a0 + a1) + (a2 + a3);
      float b0 = fmaf(Hs1[1], P[1], Hs1[0] * P[0]);
      float b1 = fmaf(Hs1[3], P[3], Hs1[2] * P[2]);
      float b2 = fmaf(Hs1[5], P[5], Hs1[4] * P[4]);
      float b3 = fmaf(Hs1[7], P[7], Hs1[6] * P[6]);
      const float hp1 = (b0 + b1) + (b2 + b3);

      // ---- HP allgather (absolute): 16 bpermute on LDS pipe ----
      float HP0[8], HP1[8];
#pragma unroll
      for (int k = 0; k < 8; ++k) {
        HP0[k] = BPERM(hp0, bp[k]);
        HP1[k] = BPERM(hp1, bp[k]);
      }

      // ---- S = HP H^T + R, local dots with SGPR H ----
      float c0 = fmaf(Hs0[1], HP0[1], Hs0[0] * HP0[0]);
      float c1 = fmaf(Hs0[3], HP0[3], Hs0[2] * HP0[2]);
      float c2 = fmaf(Hs0[5], HP0[5], Hs0[4] * HP0[4]);
      float c3 = fmaf(Hs0[7], HP0[7], Hs0[6] * HP0[6]);
      s00 = R00 + ((c0 + c1) + (c2 + c3));
      float d0 = fmaf(Hs1[1], HP0[1], Hs1[0] * HP0[0]);
      float d1 = fmaf(Hs1[3], HP0[3], Hs1[2] * HP0[2]);
      float d2 = fmaf(Hs1[5], HP0[5], Hs1[4] * HP0[4]);
      float d3 = fmaf(Hs1[7], HP0[7], Hs1[6] * HP0[6]);
      s01 = R01 + ((d0 + d1) + (d2 + d3));
      float e0 = fmaf(Hs1[1], HP1[1], Hs1[0] * HP1[0]);
      float e1 = fmaf(Hs1[3], HP1[3], Hs1[2] * HP1[2]);
      float e2 = fmaf(Hs1[5], HP1[5], Hs1[4] * HP1[4]);
      float e3 = fmaf(Hs1[7], HP1[7], Hs1[6] * HP1[6]);
      s11 = R11 + ((e0 + e1) + (e2 + e3));

      // ---- 2x2 inverse, gain column r ----
      const float det  = fmaf(s00, s11, -(s01 * s01));
      const float rdet = 1.0f / det;
      const float i00 = s11 * rdet, i01 = -s01 * rdet, i11 = s00 * rdet;
      kt0 = i00 * hp0 + i01 * hp1;
      kt1 = i01 * hp0 + i11 * hp1;

      // ---- Pu row r (absolute): Pu[j] = P[j] - kt0*HP0[j] - kt1*HP1[j] ----
      float Pu[8];
#pragma unroll
      for (int k = 0; k < 8; ++k)
        Pu[k] = fmaf(-kt0, HP0[k], fmaf(-kt1, HP1[k], P[k]));

      // ---- gather Pu rows: UPPER TRIANGLE only (Pu symmetric) ----
      float PuG[8][8];
#pragma unroll
      for (int k = 0; k < 8; ++k)
#pragma unroll
        for (int jj = k; jj < 8; ++jj)
          PuG[k][jj] = BPERM(Pu[jj], bp[k]);
#pragma unroll
      for (int k = 1; k < 8; ++k)
#pragma unroll
        for (int jj = 0; jj < k; ++jj)
          PuG[k][jj] = PuG[jj][k];   // free register mirror

      // ---- W[l] = (F Pu)[r][l] = sum_k Frow[k] * PuG[k][l] ----
      float W[8];
#pragma unroll
      for (int l = 0; l < 8; ++l) {
        float w0 = fmaf(Frow[1], PuG[1][l], Frow[0] * PuG[0][l]);
        float w1 = fmaf(Frow[3], PuG[3][l], Frow[2] * PuG[2][l]);
        float w2 = fmaf(Frow[5], PuG[5][l], Frow[4] * PuG[4][l]);
        float w3 = fmaf(Frow[7], PuG[7][l], Frow[6] * PuG[6][l]);
        W[l] = (w0 + w1) + (w2 + w3);
      }

      // ---- Pn[j] = Q[r][j] + sum_l W[l] * F[j][l]  (SGPR F) ----
      float Pn[8];
#pragma unroll
      for (int jj = 0; jj < 8; ++jj) {
        float p0 = fmaf(W[1], Fs[jj * 8 + 1], W[0] * Fs[jj * 8 + 0]);
        float p1 = fmaf(W[3], Fs[jj * 8 + 3], W[2] * Fs[jj * 8 + 2]);
        float p2 = fmaf(W[5], Fs[jj * 8 + 5], W[4] * Fs[jj * 8 + 4]);
        float p3 = fmaf(W[7], Fs[jj * 8 + 7], W[6] * Fs[jj * 8 + 6]);
        Pn[jj] = Qrow[jj] + ((p0 + p1) + (p2 + p3));
      }

      // ---- wave-uniform freeze vote (every 4th step) ----
      if (j == 3) {
        float dmax = 0.f;
#pragma unroll
        for (int c = 0; c < 8; ++c) dmax = fmaxf(dmax, fabsf(Pn[c] - P[c]));
        fz = __all(dmax < FREEZE_EPS);
      }
#pragma unroll
      for (int c = 0; c < 8; ++c) P[c] = Pn[c];

      // ---- outputs (pre-update) ----
      if (r == 0) *reinterpret_cast<float2*>(mo + 2 * t) = make_float2(mm0, mm1);
      if (r == 1) *reinterpret_cast<float4*>(co + 4 * t) = make_float4(s00, s01, s01, s11);

      // ---- mean measurement+time update ----
      const float y0 = x0 - mm0, y1 = x1 - mm1;
      const float mu = fmaf(kt0, y0, fmaf(kt1, y1, m));
      m = matvec8(Fd, mu);
    }
    xa = na; xb = nb;
    int tf = tb + 8; if (tf > NT - 4) tf = NT - 4;
    na = *reinterpret_cast<const float4*>(xg + 2 * tf);
    nb = *reinterpret_cast<const float4*>(xg + 2 * tf + 4);
    wfrozen = fz;
  }

  // ================= Phase 2: steady-state linear filter ====================
  if (tb < NT) {
    float mm0 = allred8(Hr0 * m);
    float mm1 = allred8(Hr1 * m);
    // HF rows: HF_i[r] = sum_k H_i[k] * F[k][r]  (SGPR H, per-lane Fcol)
    float u0 = fmaf(Hs0[1], Fcol[1], Hs0[0] * Fcol[0]);
    float u1 = fmaf(Hs0[3], Fcol[3], Hs0[2] * Fcol[2]);
    float u2 = fmaf(Hs0[5], Fcol[5], Hs0[4] * Fcol[4]);
    float u3 = fmaf(Hs0[7], Fcol[7], Hs0[6] * Fcol[6]);
    const float HF0r = (u0 + u1) + (u2 + u3);
    float w0 = fmaf(Hs1[1], Fcol[1], Hs1[0] * Fcol[0]);
    float w1 = fmaf(Hs1[3], Fcol[3], Hs1[2] * Fcol[2]);
    float w2 = fmaf(Hs1[5], Fcol[5], Hs1[4] * Fcol[4]);
    float w3 = fmaf(Hs1[7], Fcol[7], Hs1[6] * Fcol[6]);
    const float HF1r = (w0 + w1) + (w2 + w3);
    // HFK (octet-uniform 2x2) and FK columns (per-lane)
    const float hfk00 = allred8(HF0r * kt0), hfk01 = allred8(HF0r * kt1);
    const float hfk10 = allred8(HF1r * kt0), hfk11 = allred8(HF1r * kt1);
    const float fk0 = matvec8(Fd, kt0), fk1 = matvec8(Fd, kt1);

    // constant covariance blast: lane-strided float4
    const float4 cv = make_float4(s00, s01, s01, s11);
#pragma unroll 1
    for (int k2 = tb + r; k2 < NT; k2 += 8)
      *reinterpret_cast<float4*>(co + 4 * k2) = cv;

#pragma unroll 1
    for (; tb < NT; tb += 4) {
      float2 b0, b1, b2, b3;
#pragma unroll
      for (int j = 0; j < 4; ++j) {
        const float x0 = (j == 0) ? xa.x : (j == 1) ? xa.z : (j == 2) ? xb.x : xb.z;
        const float x1 = (j == 0) ? xa.y : (j == 1) ? xa.w : (j == 2) ? xb.y : xb.w;
        const float y0 = x0 - mm0, y1 = x1 - mm1;
        if (j == 0) b0 = make_float2(mm0, mm1);
        else if (j == 1) b1 = make_float2(mm0, mm1);
        else if (j == 2) b2 = make_float2(mm0, mm1);
        else b3 = make_float2(mm0, mm1);
        const float wa = allred8(HF0r * m);   // (HF m)[0]
        const float wb = allred8(HF1r * m);   // (HF m)[1]
        float mn = matvec8(Fd, m);            // (F m)[r]
        m = fmaf(fk0, y0, fmaf(fk1, y1, mn)); // m' = F m + FK y
        mm0 = fmaf(hfk00, y0, fmaf(hfk01, y1, wa));
        mm1 = fmaf(hfk10, y0, fmaf(hfk11, y1, wb));
      }
      if (r == 0) {
        *reinterpret_cast<float4*>(mo + 2 * tb)     = make_float4(b0.x, b0.y, b1.x, b1.y);
        *reinterpret_cast<float4*>(mo + 2 * tb + 4) = make_float4(b2.x, b2.y, b3.x, b3.y);
      }
      xa = na; xb = nb;
      int tf = tb + 8; if (tf > NT - 4) tf = NT - 4;
      na = *reinterpret_cast<const float4*>(xg + 2 * tf);
      nb = *reinterpret_cast<const float4*>(xg + 2 * tf + 4);
    }
  }
}

extern "C" void kernel_launch(void* const* d_in, const int* in_sizes, int n_in,
                              void* d_out, int out_size, void* d_ws, size_t ws_size,
                              hipStream_t stream) {
  const float* x  = (const float*)d_in[0];
  const float* m0 = (const float*)d_in[1];
  const float* P0 = (const float*)d_in[2];
  const float* F  = (const float*)d_in[3];
  const float* Q  = (const float*)d_in[4];
  const float* H  = (const float*)d_in[5];
  const float* R  = (const float*)d_in[6];
  float* out = (float*)d_out;

  dim3 grid(NG * 8 / 256), block(256);
  hipLaunchKernelGGL(kf_kernel, grid, block, 0, stream,
                     x, m0, P0, F, Q, H, R, out);
}

// Round 9
// 267.976 us; speedup vs baseline: 1.2011x; 1.2011x over previous
//
#include <hip/hip_runtime.h>

#define NG 16384
#define NT 200
#define FREEZE_EPS 3e-4f

// DPP cross-lane (VALU pipe), all within aligned 8-lane octets
#define DPPF(v, ctrl) __int_as_float(__builtin_amdgcn_update_dpp( \
    0, __float_as_int(v), (ctrl), 0xF, 0xF, true))
#define QP1(v) DPPF(v, 0xB1)   // src lane ^ 1
#define QP2(v) DPPF(v, 0x4E)   // src lane ^ 2
#define RHM(v) DPPF(v, 0x141)  // src lane ^ 7 (row_half_mirror)

__device__ __forceinline__ float allred8(float v) {
  v += QP1(v); v += QP2(v); v += RHM(v); return v;
}
// reduce-scatter butterfly: lane r ends with sum_k F[r][k]*val[k].
// Fd[s] = F[r^kd[s]][r], kd = [0,1,2,3,7,6,5,4].
__device__ __forceinline__ float matvec8(const float* __restrict__ Fd, float val) {
  float c0 = Fd[0]*val, c1 = Fd[1]*val, c2 = Fd[2]*val, c3 = Fd[3]*val;
  float c4 = Fd[4]*val, c5 = Fd[5]*val, c6 = Fd[6]*val, c7 = Fd[7]*val;
  float a0 = c0 + RHM(c4), a1 = c1 + RHM(c5), a2 = c2 + RHM(c6), a3 = c3 + RHM(c7);
  float b0 = a0 + QP2(a2), b1 = a1 + QP2(a3);
  return b0 + QP1(b1);
}

struct GS {  // per-group state, lane r holds row r (xor layout for P)
  float m;
  float P[8];   // P~[d] = P[r][r^d]
  float kt0, kt1, s00, s01, s11;
};

// One Riccati step for one group (no LDS ops; all DPP/VALU).
template <bool DO_DELTA>
__device__ __forceinline__ float2 ric_step(
    GS& s, const float* __restrict__ Hd0, const float* __restrict__ Hd1,
    const float (*__restrict__ Fde)[8], const float* __restrict__ Frt,
    const float* __restrict__ Qt, float R00, float R01, float R11,
    float& dmax) {
  // mm = H m
  const float mm0 = allred8(Hd0[0] * s.m);
  const float mm1 = allred8(Hd1[0] * s.m);

  // hp_i = (H P)[i][r] via symmetry (serial fma; partner chain hides latency)
  float hp0 = Hd0[0] * s.P[0];
  float hp1 = Hd1[0] * s.P[0];
#pragma unroll
  for (int c = 1; c < 8; ++c) {
    hp0 = fmaf(Hd0[c], s.P[c], hp0);
    hp1 = fmaf(Hd1[c], s.P[c], hp1);
  }

  // S = HP H^T + R
  s.s00 = R00 + allred8(hp0 * Hd0[0]);
  s.s01 = R01 + allred8(hp0 * Hd1[0]);
  s.s11 = R11 + allred8(hp1 * Hd1[0]);
  const float det  = fmaf(s.s00, s.s11, -(s.s01 * s.s01));
  const float rdet = 1.0f / det;
  const float i00 = s.s11 * rdet, i01 = -s.s01 * rdet, i11 = s.s00 * rdet;
  s.kt0 = i00 * hp0 + i01 * hp1;
  s.kt1 = i01 * hp0 + i11 * hp1;

  // allgather hp into xor slots: G[d] = hp @ lane r^d
  float G0[8], G1[8];
  G0[0] = hp0;        G1[0] = hp1;
  G0[1] = QP1(hp0);   G1[1] = QP1(hp1);
  G0[2] = QP2(hp0);   G1[2] = QP2(hp1);
  G0[3] = QP2(G0[1]); G1[3] = QP2(G1[1]);
  G0[7] = RHM(hp0);   G1[7] = RHM(hp1);
  G0[6] = RHM(G0[1]); G1[6] = RHM(G1[1]);
  G0[5] = RHM(G0[2]); G1[5] = RHM(G1[2]);
  G0[4] = RHM(G0[3]); G1[4] = RHM(G1[3]);

  // Pu~[d] = P~[d] - kt0*G0[d] - kt1*G1[d]
  float Pu[8];
#pragma unroll
  for (int d = 0; d < 8; ++d)
    Pu[d] = fmaf(-s.kt0, G0[d], fmaf(-s.kt1, G1[d], s.P[d]));

  // V~[dl] = sum_c Pu~[c] * Fde[dl][c]  (all-local, serial fma)
  float V[8];
#pragma unroll
  for (int dl = 0; dl < 8; ++dl) {
    float acc = Pu[0] * Fde[dl][0];
#pragma unroll
    for (int c = 1; c < 8; ++c) acc = fmaf(Pu[c], Fde[dl][c], acc);
    V[dl] = acc;
  }

  // Pn~[d] = Qt[d] + sum_e Frt[e] * (V~ @ lane r^e)[e^d]  (DPP xor-tree)
  float Pn[8], A1[8], A2[8], A3[8], T[8];
#pragma unroll
  for (int d = 0; d < 8; ++d) Pn[d] = fmaf(Frt[0], V[d], Qt[d]);
#pragma unroll
  for (int c = 0; c < 8; ++c) A1[c] = QP1(V[c]);
#pragma unroll
  for (int d = 0; d < 8; ++d) Pn[d] = fmaf(Frt[1], A1[1 ^ d], Pn[d]);
#pragma unroll
  for (int c = 0; c < 8; ++c) A2[c] = QP2(V[c]);
#pragma unroll
  for (int d = 0; d < 8; ++d) Pn[d] = fmaf(Frt[2], A2[2 ^ d], Pn[d]);
#pragma unroll
  for (int c = 0; c < 8; ++c) A3[c] = QP2(A1[c]);
#pragma unroll
  for (int d = 0; d < 8; ++d) Pn[d] = fmaf(Frt[3], A3[3 ^ d], Pn[d]);
#pragma unroll
  for (int c = 0; c < 8; ++c) T[c] = RHM(V[c]);
#pragma unroll
  for (int d = 0; d < 8; ++d) Pn[d] = fmaf(Frt[7], T[7 ^ d], Pn[d]);
#pragma unroll
  for (int c = 0; c < 8; ++c) T[c] = RHM(A1[c]);
#pragma unroll
  for (int d = 0; d < 8; ++d) Pn[d] = fmaf(Frt[6], T[6 ^ d], Pn[d]);
#pragma unroll
  for (int c = 0; c < 8; ++c) T[c] = RHM(A2[c]);
#pragma unroll
  for (int d = 0; d < 8; ++d) Pn[d] = fmaf(Frt[5], T[5 ^ d], Pn[d]);
#pragma unroll
  for (int c = 0; c < 8; ++c) T[c] = RHM(A3[c]);
#pragma unroll
  for (int d = 0; d < 8; ++d) Pn[d] = fmaf(Frt[4], T[4 ^ d], Pn[d]);

  if (DO_DELTA) {
#pragma unroll
    for (int c = 0; c < 8; ++c) dmax = fmaxf(dmax, fabsf(Pn[c] - s.P[c]));
  }
#pragma unroll
  for (int c = 0; c < 8; ++c) s.P[c] = Pn[c];
  return make_float2(mm0, mm1);
}

__global__ __launch_bounds__(256, 1)
void kf_kernel(const float* __restrict__ x,
               const float* __restrict__ m0,
               const float* __restrict__ P0,
               const float* __restrict__ Fm,
               const float* __restrict__ Qm,
               const float* __restrict__ Hm,
               const float* __restrict__ Rm,
               float* __restrict__ out) {
  const int tid = threadIdx.x;
  const int r   = tid & 7;
  // two groups per octet: gA and gB = gA + 8; 16 groups per wave
  const int gA = blockIdx.x * 64 + (tid >> 6) * 16 + ((tid & 63) >> 3);
  const int gB = gA + 8;

  // ---- shared per-lane tables (identical for both groups) ----
  constexpr int kD[8] = {0, 1, 2, 3, 7, 6, 5, 4};
  float Fd[8];
#pragma unroll
  for (int s = 0; s < 8; ++s) Fd[s] = Fm[((r ^ kD[s]) << 3) | r];
  float Frt[8], Qt[8], Hd0[8], Hd1[8];
#pragma unroll
  for (int c = 0; c < 8; ++c) {
    Frt[c] = Fm[(r << 3) | (r ^ c)];
    Qt[c]  = Qm[(r << 3) | (r ^ c)];
    Hd0[c] = Hm[r ^ c];
    Hd1[c] = Hm[8 + (r ^ c)];
  }
  const float R00 = Rm[0], R01 = Rm[1], R11 = Rm[3];

  // ---- Fde[dl][c] = F[r^dl][r^c] via DPP chains (shared) ----
  float Fde[8][8];
  {
    float t1[8], t2[8], t3[8], tt[8];
#pragma unroll
    for (int c = 0; c < 8; ++c) Fde[0][c] = Frt[c];
#pragma unroll
    for (int c = 0; c < 8; ++c) t1[c] = QP1(Frt[c]);
#pragma unroll
    for (int c = 0; c < 8; ++c) Fde[1][c] = t1[1 ^ c];
#pragma unroll
    for (int c = 0; c < 8; ++c) t2[c] = QP2(Frt[c]);
#pragma unroll
    for (int c = 0; c < 8; ++c) Fde[2][c] = t2[2 ^ c];
#pragma unroll
    for (int c = 0; c < 8; ++c) t3[c] = QP2(t1[c]);
#pragma unroll
    for (int c = 0; c < 8; ++c) Fde[3][c] = t3[3 ^ c];
#pragma unroll
    for (int c = 0; c < 8; ++c) tt[c] = RHM(Frt[c]);
#pragma unroll
    for (int c = 0; c < 8; ++c) Fde[7][c] = tt[7 ^ c];
#pragma unroll
    for (int c = 0; c < 8; ++c) tt[c] = RHM(t1[c]);
#pragma unroll
    for (int c = 0; c < 8; ++c) Fde[6][c] = tt[6 ^ c];
#pragma unroll
    for (int c = 0; c < 8; ++c) tt[c] = RHM(t2[c]);
#pragma unroll
    for (int c = 0; c < 8; ++c) Fde[5][c] = tt[5 ^ c];
#pragma unroll
    for (int c = 0; c < 8; ++c) tt[c] = RHM(t3[c]);
#pragma unroll
    for (int c = 0; c < 8; ++c) Fde[4][c] = tt[4 ^ c];
  }

  // ---- per-group states ----
  GS A, B;
  A.m = m0[(size_t)gA * 8 + r];
  B.m = m0[(size_t)gB * 8 + r];
#pragma unroll
  for (int d = 0; d < 8; ++d) {
    A.P[d] = P0[(size_t)gA * 64 + (r << 3) + (r ^ d)];
    B.P[d] = P0[(size_t)gB * 64 + (r << 3) + (r ^ d)];
  }
  A.kt0 = A.kt1 = A.s00 = A.s01 = A.s11 = 0.f;
  B.kt0 = B.kt1 = B.s00 = B.s01 = B.s11 = 0.f;

  const float* xgA = x + (size_t)gA * NT * 2;
  const float* xgB = x + (size_t)gB * NT * 2;
  float* moA = out + (size_t)gA * NT * 2;
  float* moB = out + (size_t)gB * NT * 2;
  float* coA = out + (size_t)NG * NT * 2 + (size_t)gA * NT * 4;
  float* coB = out + (size_t)NG * NT * 2 + (size_t)gB * NT * 4;

  // ---- x prefetch: 4-step batches per group ----
  float4 xaA = *reinterpret_cast<const float4*>(xgA);
  float4 xbA = *reinterpret_cast<const float4*>(xgA + 4);
  float4 naA = *reinterpret_cast<const float4*>(xgA + 8);
  float4 nbA = *reinterpret_cast<const float4*>(xgA + 12);
  float4 xaB = *reinterpret_cast<const float4*>(xgB);
  float4 xbB = *reinterpret_cast<const float4*>(xgB + 4);
  float4 naB = *reinterpret_cast<const float4*>(xgB + 8);
  float4 nbB = *reinterpret_cast<const float4*>(xgB + 12);

  int tb = 0;
  bool wfrozen = false;

  // ================= Phase 1: Riccati (until wave-uniform freeze) ==========
#pragma unroll 1
  for (; tb < NT && !wfrozen; tb += 4) {
    float dmax = 0.f;
#pragma unroll
    for (int j = 0; j < 4; ++j) {
      const int t = tb + j;
      const float xA0 = (j == 0) ? xaA.x : (j == 1) ? xaA.z : (j == 2) ? xbA.x : xbA.z;
      const float xA1 = (j == 0) ? xaA.y : (j == 1) ? xaA.w : (j == 2) ? xbA.y : xbA.w;
      const float xB0 = (j == 0) ? xaB.x : (j == 1) ? xaB.z : (j == 2) ? xbB.x : xbB.z;
      const float xB1 = (j == 0) ? xaB.y : (j == 1) ? xaB.w : (j == 2) ? xbB.y : xbB.w;

      float2 mmA, mmB;
      if (j == 3) {
        mmA = ric_step<true>(A, Hd0, Hd1, Fde, Frt, Qt, R00, R01, R11, dmax);
        mmB = ric_step<true>(B, Hd0, Hd1, Fde, Frt, Qt, R00, R01, R11, dmax);
      } else {
        mmA = ric_step<false>(A, Hd0, Hd1, Fde, Frt, Qt, R00, R01, R11, dmax);
        mmB = ric_step<false>(B, Hd0, Hd1, Fde, Frt, Qt, R00, R01, R11, dmax);
      }

      // outputs (pre-update), spread across lanes 0..3
      if (r == 0)      *reinterpret_cast<float2*>(moA + 2 * t) = mmA;
      else if (r == 1) *reinterpret_cast<float4*>(coA + 4 * t) = make_float4(A.s00, A.s01, A.s01, A.s11);
      else if (r == 2) *reinterpret_cast<float2*>(moB + 2 * t) = mmB;
      else if (r == 3) *reinterpret_cast<float4*>(coB + 4 * t) = make_float4(B.s00, B.s01, B.s01, B.s11);

      // mean measurement+time update
      const float yA0 = xA0 - mmA.x, yA1 = xA1 - mmA.y;
      const float yB0 = xB0 - mmB.x, yB1 = xB1 - mmB.y;
      const float muA = fmaf(A.kt0, yA0, fmaf(A.kt1, yA1, A.m));
      const float muB = fmaf(B.kt0, yB0, fmaf(B.kt1, yB1, B.m));
      A.m = matvec8(Fd, muA);
      B.m = matvec8(Fd, muB);
    }
    xaA = naA; xbA = nbA; xaB = naB; xbB = nbB;
    int tf = tb + 8; if (tf > NT - 4) tf = NT - 4;
    naA = *reinterpret_cast<const float4*>(xgA + 2 * tf);
    nbA = *reinterpret_cast<const float4*>(xgA + 2 * tf + 4);
    naB = *reinterpret_cast<const float4*>(xgB + 2 * tf);
    nbB = *reinterpret_cast<const float4*>(xgB + 2 * tf + 4);
    wfrozen = (__all(dmax < FREEZE_EPS) != 0);
  }

  // ================= Phase 2: steady-state linear filter ====================
  if (tb < NT) {
    float mmA0 = allred8(Hd0[0] * A.m);
    float mmA1 = allred8(Hd1[0] * A.m);
    float mmB0 = allred8(Hd0[0] * B.m);
    float mmB1 = allred8(Hd1[0] * B.m);
    // HF rows (shared per-lane): HF_i[r] = sum_e H_i[r^e] * F[r^e][r]
    float HF0r = Hd0[0] * Fde[0][0];
    float HF1r = Hd1[0] * Fde[0][0];
#pragma unroll
    for (int e = 1; e < 8; ++e) {
      HF0r = fmaf(Hd0[e], Fde[e][0], HF0r);
      HF1r = fmaf(Hd1[e], Fde[e][0], HF1r);
    }
    // per-group steady constants
    const float hfkA00 = allred8(HF0r * A.kt0), hfkA01 = allred8(HF0r * A.kt1);
    const float hfkA10 = allred8(HF1r * A.kt0), hfkA11 = allred8(HF1r * A.kt1);
    const float hfkB00 = allred8(HF0r * B.kt0), hfkB01 = allred8(HF0r * B.kt1);
    const float hfkB10 = allred8(HF1r * B.kt0), hfkB11 = allred8(HF1r * B.kt1);
    const float fkA0 = matvec8(Fd, A.kt0), fkA1 = matvec8(Fd, A.kt1);
    const float fkB0 = matvec8(Fd, B.kt0), fkB1 = matvec8(Fd, B.kt1);

    // constant covariance blast (lane-strided float4, both groups)
    const float4 cvA = make_float4(A.s00, A.s01, A.s01, A.s11);
    const float4 cvB = make_float4(B.s00, B.s01, B.s01, B.s11);
#pragma unroll 1
    for (int k2 = tb + r; k2 < NT; k2 += 8) {
      *reinterpret_cast<float4*>(coA + 4 * k2) = cvA;
      *reinterpret_cast<float4*>(coB + 4 * k2) = cvB;
    }

#pragma unroll 1
    for (; tb < NT; tb += 4) {
      float2 a0, a1, a2, a3, b0, b1, b2, b3;
#pragma unroll
      for (int j = 0; j < 4; ++j) {
        const float xA0 = (j == 0) ? xaA.x : (j == 1) ? xaA.z : (j == 2) ? xbA.x : xbA.z;
        const float xA1 = (j == 0) ? xaA.y : (j == 1) ? xaA.w : (j == 2) ? xbA.y : xbA.w;
        const float xB0 = (j == 0) ? xaB.x : (j == 1) ? xaB.z : (j == 2) ? xbB.x : xbB.z;
        const float xB1 = (j == 0) ? xaB.y : (j == 1) ? xaB.w : (j == 2) ? xbB.y : xbB.w;
        if (j == 0) { a0 = make_float2(mmA0, mmA1); b0 = make_float2(mmB0, mmB1); }
        else if (j == 1) { a1 = make_float2(mmA0, mmA1); b1 = make_float2(mmB0, mmB1); }
        else if (j == 2) { a2 = make_float2(mmA0, mmA1); b2 = make_float2(mmB0, mmB1); }
        else { a3 = make_float2(mmA0, mmA1); b3 = make_float2(mmB0, mmB1); }
        const float yA0 = xA0 - mmA0, yA1 = xA1 - mmA1;
        const float yB0 = xB0 - mmB0, yB1 = xB1 - mmB1;
        const float waA = allred8(HF0r * A.m);
        const float wbA = allred8(HF1r * A.m);
        const float waB = allred8(HF0r * B.m);
        const float wbB = allred8(HF1r * B.m);
        const float mnA = matvec8(Fd, A.m);
        const float mnB = matvec8(Fd, B.m);
        A.m = fmaf(fkA0, yA0, fmaf(fkA1, yA1, mnA));
        B.m = fmaf(fkB0, yB0, fmaf(fkB1, yB1, mnB));
        mmA0 = fmaf(hfkA00, yA0, fmaf(hfkA01, yA1, waA));
        mmA1 = fmaf(hfkA10, yA0, fmaf(hfkA11, yA1, wbA));
        mmB0 = fmaf(hfkB00, yB0, fmaf(hfkB01, yB1, waB));
        mmB1 = fmaf(hfkB10, yB0, fmaf(hfkB11, yB1, wbB));
      }
      if (r == 0) {
        *reinterpret_cast<float4*>(moA + 2 * tb)     = make_float4(a0.x, a0.y, a1.x, a1.y);
        *reinterpret_cast<float4*>(moA + 2 * tb + 4) = make_float4(a2.x, a2.y, a3.x, a3.y);
      } else if (r == 2) {
        *reinterpret_cast<float4*>(moB + 2 * tb)     = make_float4(b0.x, b0.y, b1.x, b1.y);
        *reinterpret_cast<float4*>(moB + 2 * tb + 4) = make_float4(b2.x, b2.y, b3.x, b3.y);
      }
      xaA = naA; xbA = nbA; xaB = naB; xbB = nbB;
      int tf = tb + 8; if (tf > NT - 4) tf = NT - 4;
      naA = *reinterpret_cast<const float4*>(xgA + 2 * tf);
      nbA = *reinterpret_cast<const float4*>(xgA + 2 * tf + 4);
      naB = *reinterpret_cast<const float4*>(xgB + 2 * tf);
      nbB = *reinterpret_cast<const float4*>(xgB + 2 * tf + 4);
    }
  }
}

extern "C" void kernel_launch(void* const* d_in, const int* in_sizes, int n_in,
                              void* d_out, int out_size, void* d_ws, size_t ws_size,
                              hipStream_t stream) {
  const float* x  = (const float*)d_in[0];
  const float* m0 = (const float*)d_in[1];
  const float* P0 = (const float*)d_in[2];
  const float* F  = (const float*)d_in[3];
  const float* Q  = (const float*)d_in[4];
  const float* H  = (const float*)d_in[5];
  const float* R  = (const float*)d_in[6];
  float* out = (float*)d_out;

  dim3 grid(NG / 64), block(256);
  hipLaunchKernelGGL(kf_kernel, grid, block, 0, stream,
                     x, m0, P0, F, Q, H, R, out);
}

// Round 10
// 190.669 us; speedup vs baseline: 1.6881x; 1.4055x over previous
//
#include <hip/hip_runtime.h>

#define NG 16384
#define NT 200
#define FREEZE_EPS 3e-4f

// DPP cross-lane (VALU pipe), all within aligned 8-lane octets
#define DPPF(v, ctrl) __int_as_float(__builtin_amdgcn_update_dpp( \
    0, __float_as_int(v), (ctrl), 0xF, 0xF, true))
#define QP1(v) DPPF(v, 0xB1)   // src lane ^ 1
#define QP2(v) DPPF(v, 0x4E)   // src lane ^ 2
#define RHM(v) DPPF(v, 0x141)  // src lane ^ 7 (row_half_mirror)

__device__ __forceinline__ float allmax8(float v) {
  v = fmaxf(v, QP1(v)); v = fmaxf(v, QP2(v)); v = fmaxf(v, RHM(v)); return v;
}
// xor-allgather: o[e] = v @ lane (r^e)  (7 DPP)
__device__ __forceinline__ void gather8(float v, float* __restrict__ o) {
  o[0] = v;
  o[1] = QP1(v);
  o[2] = QP2(v);
  o[3] = QP2(o[1]);
  o[7] = RHM(v);
  o[6] = RHM(o[1]);
  o[5] = RHM(o[2]);
  o[4] = RHM(o[3]);
}

__global__ __launch_bounds__(256, 2)
void kf_kernel(const float* __restrict__ x,
               const float* __restrict__ m0,
               const float* __restrict__ P0,
               const float* __restrict__ Fm,
               const float* __restrict__ Qm,
               const float* __restrict__ Hm,
               const float* __restrict__ Rm,
               float* __restrict__ out) {
  const int tid = threadIdx.x;
  const int r   = tid & 7;
  const int g   = blockIdx.x * 32 + (tid >> 3);

  // ---- per-lane xor-indexed parameter tables ----
  float Frt[8], Qt[8], Hd0[8], Hd1[8];
#pragma unroll
  for (int c = 0; c < 8; ++c) {
    Frt[c] = Fm[(r << 3) | (r ^ c)];   // F[r][r^c]
    Qt[c]  = Qm[(r << 3) | (r ^ c)];   // Q[r][r^c]
    Hd0[c] = Hm[r ^ c];                // H[0][r^c]
    Hd1[c] = Hm[8 + (r ^ c)];          // H[1][r^c]
  }
  const float R00 = Rm[0], R01 = Rm[1], R11 = Rm[3];

  // ---- Fde[dl][c] = F[r^dl][r^c] via DPP chains (one-time) ----
  float Fde[8][8];
  {
    float t1[8], t2[8], t3[8], tt[8];
#pragma unroll
    for (int c = 0; c < 8; ++c) Fde[0][c] = Frt[c];
#pragma unroll
    for (int c = 0; c < 8; ++c) t1[c] = QP1(Frt[c]);
#pragma unroll
    for (int c = 0; c < 8; ++c) Fde[1][c] = t1[1 ^ c];
#pragma unroll
    for (int c = 0; c < 8; ++c) t2[c] = QP2(Frt[c]);
#pragma unroll
    for (int c = 0; c < 8; ++c) Fde[2][c] = t2[2 ^ c];
#pragma unroll
    for (int c = 0; c < 8; ++c) t3[c] = QP2(t1[c]);
#pragma unroll
    for (int c = 0; c < 8; ++c) Fde[3][c] = t3[3 ^ c];
#pragma unroll
    for (int c = 0; c < 8; ++c) tt[c] = RHM(Frt[c]);
#pragma unroll
    for (int c = 0; c < 8; ++c) Fde[7][c] = tt[7 ^ c];
#pragma unroll
    for (int c = 0; c < 8; ++c) tt[c] = RHM(t1[c]);
#pragma unroll
    for (int c = 0; c < 8; ++c) Fde[6][c] = tt[6 ^ c];
#pragma unroll
    for (int c = 0; c < 8; ++c) tt[c] = RHM(t2[c]);
#pragma unroll
    for (int c = 0; c < 8; ++c) Fde[5][c] = tt[5 ^ c];
#pragma unroll
    for (int c = 0; c < 8; ++c) tt[c] = RHM(t3[c]);
#pragma unroll
    for (int c = 0; c < 8; ++c) Fde[4][c] = tt[4 ^ c];
  }

  // ---- HFd tables: HFd_i[e] = (H F)[i][r^e]  (one-time, 14 DPP) ----
  float HFd0[8], HFd1[8];
  {
    float Hs0[8], Hs1[8];
#pragma unroll
    for (int i = 0; i < 8; ++i) { Hs0[i] = Hm[i]; Hs1[i] = Hm[8 + i]; }
    float hfc0 = 0.f, hfc1 = 0.f;   // (H F)[i][r]
#pragma unroll
    for (int jj = 0; jj < 8; ++jj) {
      const float fc = Fm[(jj << 3) | r];   // F[jj][r]
      hfc0 = fmaf(Hs0[jj], fc, hfc0);
      hfc1 = fmaf(Hs1[jj], fc, hfc1);
    }
    gather8(hfc0, HFd0);
    gather8(hfc1, HFd1);
  }

  // ---- per-group state: lane r holds m[r] and P~[d] = P[r][r^d] ----
  float m = m0[(size_t)g * 8 + r];
  float P[8];
#pragma unroll
  for (int d = 0; d < 8; ++d)
    P[d] = P0[(size_t)g * 64 + (r << 3) + (r ^ d)];

  const float* xg = x + (size_t)g * NT * 2;
  float* mo = out + (size_t)g * NT * 2;
  float* co = out + (size_t)NG * NT * 2 + (size_t)g * NT * 4;

  // ---- init measurement mean mm = H m (one-time gather) ----
  float mm0, mm1;
  {
    float MU[8];
    gather8(m, MU);
    float a = Hd0[0] * MU[0], b = Hd1[0] * MU[0];
#pragma unroll
    for (int e = 1; e < 8; ++e) {
      a = fmaf(Hd0[e], MU[e], a);
      b = fmaf(Hd1[e], MU[e], b);
    }
    mm0 = a; mm1 = b;
  }

  float kt0 = 0.f, kt1 = 0.f, s00 = 0.f, s01 = 0.f, s11 = 0.f;

  // ---- x double-buffer: 4-step batches ----
  float4 xa = *reinterpret_cast<const float4*>(xg);
  float4 xb = *reinterpret_cast<const float4*>(xg + 4);
  float4 na = *reinterpret_cast<const float4*>(xg + 8);
  float4 nb = *reinterpret_cast<const float4*>(xg + 12);

  int tb = 0;
  bool wfrozen = false;

  // ================= Phase 1: Riccati (until wave-uniform freeze) ==========
#pragma unroll 1
  for (; tb < NT && !wfrozen; tb += 4) {
    float dmax = 0.f;
#pragma unroll
    for (int j = 0; j < 4; ++j) {
      const int t = tb + j;
      const float x0 = (j == 0) ? xa.x : (j == 1) ? xa.z : (j == 2) ? xb.x : xb.z;
      const float x1 = (j == 0) ? xa.y : (j == 1) ? xa.w : (j == 2) ? xb.y : xb.w;

      // ---- hp_i = (H P)[i][r] via P symmetry (local) ----
      float hp0 = Hd0[0] * P[0];
      float hp1 = Hd1[0] * P[0];
#pragma unroll
      for (int c = 1; c < 8; ++c) {
        hp0 = fmaf(Hd0[c], P[c], hp0);
        hp1 = fmaf(Hd1[c], P[c], hp1);
      }

      // ---- allgather hp (14 DPP) ----
      float G0[8], G1[8];
      gather8(hp0, G0);
      gather8(hp1, G1);

      // ---- S = HP H^T + R  (local redundant dots, 0 DPP) ----
      float sa = G0[0] * Hd0[0], sb = G0[0] * Hd1[0], sc = G1[0] * Hd1[0];
#pragma unroll
      for (int e = 1; e < 8; ++e) {
        sa = fmaf(G0[e], Hd0[e], sa);
        sb = fmaf(G0[e], Hd1[e], sb);
        sc = fmaf(G1[e], Hd1[e], sc);
      }
      s00 = R00 + sa; s01 = R01 + sb; s11 = R11 + sc;

      // ---- 2x2 inverse, gain column r ----
      const float det  = fmaf(s00, s11, -(s01 * s01));
      const float rdet = 1.0f / det;
      const float i00 = s11 * rdet, i01 = -s01 * rdet, i11 = s00 * rdet;
      kt0 = i00 * hp0 + i01 * hp1;
      kt1 = i01 * hp0 + i11 * hp1;

      // ---- Pu~[d] = P~[d] - kt0*G0[d] - kt1*G1[d] ----
      float Pu[8];
#pragma unroll
      for (int d = 0; d < 8; ++d)
        Pu[d] = fmaf(-kt0, G0[d], fmaf(-kt1, G1[d], P[d]));

      // ---- C = F Pu (columns, local): Ct[e] = C[r^e][r] ----
      float Ct[8];
#pragma unroll
      for (int e = 0; e < 8; ++e) {
        float acc = Fde[e][0] * Pu[0];
#pragma unroll
        for (int d = 1; d < 8; ++d) acc = fmaf(Fde[e][d], Pu[d], acc);
        Ct[e] = acc;
      }

      // ---- transpose via per-register lane-xor (12 DPP): Crow[e] = C[r][r^e] ----
      float Crow[8];
      Crow[0] = Ct[0];
      Crow[1] = QP1(Ct[1]);
      Crow[2] = QP2(Ct[2]);
      {
        const float t3a = QP1(Ct[3]);
        Crow[3] = QP2(t3a);
        const float t4a = QP1(Ct[4]);
        const float t4b = QP2(t4a);
        Crow[4] = RHM(t4b);
        const float t5a = QP2(Ct[5]);
        Crow[5] = RHM(t5a);
        const float t6a = QP1(Ct[6]);
        Crow[6] = RHM(t6a);
        Crow[7] = RHM(Ct[7]);
      }

      // ---- Pn~[d] = Qt[d] + sum_e Fde[d][e] * Crow[e]  (local) ----
      float Pn[8];
#pragma unroll
      for (int d = 0; d < 8; ++d) {
        float acc = Qt[d];
#pragma unroll
        for (int e = 0; e < 8; ++e) acc = fmaf(Fde[d][e], Crow[e], acc);
        Pn[d] = acc;
      }

      // ---- freeze metric (every 4th step) ----
      if (j == 3) {
        float dm = 0.f;
#pragma unroll
        for (int c = 0; c < 8; ++c) dm = fmaxf(dm, fabsf(Pn[c] - P[c]));
        dmax = dm;
      }
#pragma unroll
      for (int c = 0; c < 8; ++c) P[c] = Pn[c];

      // ---- outputs (pre-update) ----
      if (r == 0) *reinterpret_cast<float2*>(mo + 2 * t) = make_float2(mm0, mm1);
      if (r == 1) *reinterpret_cast<float4*>(co + 4 * t) = make_float4(s00, s01, s01, s11);

      // ---- mean + measurement-mean recursion (7 DPP) ----
      const float y0 = x0 - mm0, y1 = x1 - mm1;
      const float mu = fmaf(kt0, y0, fmaf(kt1, y1, m));
      float MU[8];
      gather8(mu, MU);
      float ma = Frt[0] * MU[0], h0 = HFd0[0] * MU[0], h1 = HFd1[0] * MU[0];
#pragma unroll
      for (int e = 1; e < 8; ++e) {
        ma = fmaf(Frt[e],  MU[e], ma);
        h0 = fmaf(HFd0[e], MU[e], h0);
        h1 = fmaf(HFd1[e], MU[e], h1);
      }
      m = ma; mm0 = h0; mm1 = h1;
    }
    xa = na; xb = nb;
    int tf = tb + 8; if (tf > NT - 4) tf = NT - 4;
    na = *reinterpret_cast<const float4*>(xg + 2 * tf);
    nb = *reinterpret_cast<const float4*>(xg + 2 * tf + 4);
    wfrozen = (__all(dmax < FREEZE_EPS) != 0);
  }

  // ================= Phase 2: steady-state linear filter ====================
  if (tb < NT) {
    // constant covariance blast: lane-strided float4
    const float4 cv = make_float4(s00, s01, s01, s11);
#pragma unroll 1
    for (int k2 = tb + r; k2 < NT; k2 += 8)
      *reinterpret_cast<float4*>(co + 4 * k2) = cv;

#pragma unroll 1
    for (; tb < NT; tb += 4) {
      float2 b0, b1, b2, b3;
#pragma unroll
      for (int j = 0; j < 4; ++j) {
        const float x0 = (j == 0) ? xa.x : (j == 1) ? xa.z : (j == 2) ? xb.x : xb.z;
        const float x1 = (j == 0) ? xa.y : (j == 1) ? xa.w : (j == 2) ? xb.y : xb.w;
        if (j == 0) b0 = make_float2(mm0, mm1);
        else if (j == 1) b1 = make_float2(mm0, mm1);
        else if (j == 2) b2 = make_float2(mm0, mm1);
        else b3 = make_float2(mm0, mm1);
        const float y0 = x0 - mm0, y1 = x1 - mm1;
        const float mu = fmaf(kt0, y0, fmaf(kt1, y1, m));
        float MU[8];
        gather8(mu, MU);
        float ma = Frt[0] * MU[0], h0 = HFd0[0] * MU[0], h1 = HFd1[0] * MU[0];
#pragma unroll
        for (int e = 1; e < 8; ++e) {
          ma = fmaf(Frt[e],  MU[e], ma);
          h0 = fmaf(HFd0[e], MU[e], h0);
          h1 = fmaf(HFd1[e], MU[e], h1);
        }
        m = ma; mm0 = h0; mm1 = h1;
      }
      if (r == 0) {
        *reinterpret_cast<float4*>(mo + 2 * tb)     = make_float4(b0.x, b0.y, b1.x, b1.y);
        *reinterpret_cast<float4*>(mo + 2 * tb + 4) = make_float4(b2.x, b2.y, b3.x, b3.y);
      }
      xa = na; xb = nb;
      int tf = tb + 8; if (tf > NT - 4) tf = NT - 4;
      na = *reinterpret_cast<const float4*>(xg + 2 * tf);
      nb = *reinterpret_cast<const float4*>(xg + 2 * tf + 4);
    }
  }
}

extern "C" void kernel_launch(void* const* d_in, const int* in_sizes, int n_in,
                              void* d_out, int out_size, void* d_ws, size_t ws_size,
                              hipStream_t stream) {
  const float* x  = (const float*)d_in[0];
  const float* m0 = (const float*)d_in[1];
  const float* P0 = (const float*)d_in[2];
  const float* F  = (const float*)d_in[3];
  const float* Q  = (const float*)d_in[4];
  const float* H  = (const float*)d_in[5];
  const float* R  = (const float*)d_in[6];
  float* out = (float*)d_out;

  dim3 grid(NG * 8 / 256), block(256);
  hipLaunchKernelGGL(kf_kernel, grid, block, 0, stream,
                     x, m0, P0, F, Q, H, R, out);
}

// Round 11
// 163.560 us; speedup vs baseline: 1.9679x; 1.1657x over previous
//
#include <hip/hip_runtime.h>

#define NG 16384
#define NT 200
#define FREEZE_EPS 3e-4f

// DPP cross-lane (VALU pipe) — used only where rare/off critical path
#define DPPF(v, ctrl) __int_as_float(__builtin_amdgcn_update_dpp( \
    0, __float_as_int(v), (ctrl), 0xF, 0xF, true))
#define QP1(v) DPPF(v, 0xB1)   // src lane ^ 1
#define QP2(v) DPPF(v, 0x4E)   // src lane ^ 2
#define RHM(v) DPPF(v, 0x141)  // src lane ^ 7
// LDS-pipe xor-shuffle: lane r reads lane r^e (BitMode: and=0x1f, or=0, xor=e)
#define SWZ(v, e) __int_as_float(__builtin_amdgcn_ds_swizzle( \
    __float_as_int(v), ((e) << 10) | 0x1F))

// xor-allgather via DPP (7 ops) — for one-time init / light phase-2
__device__ __forceinline__ void gather8(float v, float* __restrict__ o) {
  o[0] = v;
  o[1] = QP1(v);
  o[2] = QP2(v);
  o[3] = QP2(o[1]);
  o[7] = RHM(v);
  o[6] = RHM(o[1]);
  o[5] = RHM(o[2]);
  o[4] = RHM(o[3]);
}
// xor-allgather via ds_swizzle (7 LDS-pipe ops, all independent)
__device__ __forceinline__ void gatherS(float v, float* __restrict__ o) {
  o[0] = v;
  o[1] = SWZ(v, 1); o[2] = SWZ(v, 2); o[3] = SWZ(v, 3); o[4] = SWZ(v, 4);
  o[5] = SWZ(v, 5); o[6] = SWZ(v, 6); o[7] = SWZ(v, 7);
}

__global__ __launch_bounds__(256, 2)
void kf_kernel(const float* __restrict__ x,
               const float* __restrict__ m0,
               const float* __restrict__ P0,
               const float* __restrict__ Fm,
               const float* __restrict__ Qm,
               const float* __restrict__ Hm,
               const float* __restrict__ Rm,
               float* __restrict__ out) {
  const int tid = threadIdx.x;
  const int r   = tid & 7;
  const int g   = blockIdx.x * 32 + (tid >> 3);

  // ---- per-lane xor-indexed parameter tables ----
  float Frt[8], Qt[8], Hd0[8], Hd1[8];
#pragma unroll
  for (int c = 0; c < 8; ++c) {
    Frt[c] = Fm[(r << 3) | (r ^ c)];   // F[r][r^c]
    Qt[c]  = Qm[(r << 3) | (r ^ c)];   // Q[r][r^c]
    Hd0[c] = Hm[r ^ c];                // H[0][r^c]
    Hd1[c] = Hm[8 + (r ^ c)];          // H[1][r^c]
  }
  const float R00 = Rm[0], R01 = Rm[1], R11 = Rm[3];

  // ---- Fde[dl][c] = F[r^dl][r^c] via DPP chains (one-time) ----
  float Fde[8][8];
  {
    float t1[8], t2[8], t3[8], tt[8];
#pragma unroll
    for (int c = 0; c < 8; ++c) Fde[0][c] = Frt[c];
#pragma unroll
    for (int c = 0; c < 8; ++c) t1[c] = QP1(Frt[c]);
#pragma unroll
    for (int c = 0; c < 8; ++c) Fde[1][c] = t1[1 ^ c];
#pragma unroll
    for (int c = 0; c < 8; ++c) t2[c] = QP2(Frt[c]);
#pragma unroll
    for (int c = 0; c < 8; ++c) Fde[2][c] = t2[2 ^ c];
#pragma unroll
    for (int c = 0; c < 8; ++c) t3[c] = QP2(t1[c]);
#pragma unroll
    for (int c = 0; c < 8; ++c) Fde[3][c] = t3[3 ^ c];
#pragma unroll
    for (int c = 0; c < 8; ++c) tt[c] = RHM(Frt[c]);
#pragma unroll
    for (int c = 0; c < 8; ++c) Fde[7][c] = tt[7 ^ c];
#pragma unroll
    for (int c = 0; c < 8; ++c) tt[c] = RHM(t1[c]);
#pragma unroll
    for (int c = 0; c < 8; ++c) Fde[6][c] = tt[6 ^ c];
#pragma unroll
    for (int c = 0; c < 8; ++c) tt[c] = RHM(t2[c]);
#pragma unroll
    for (int c = 0; c < 8; ++c) Fde[5][c] = tt[5 ^ c];
#pragma unroll
    for (int c = 0; c < 8; ++c) tt[c] = RHM(t3[c]);
#pragma unroll
    for (int c = 0; c < 8; ++c) Fde[4][c] = tt[4 ^ c];
  }

  // ---- HFd tables: HFd_i[e] = (H F)[i][r^e]  (one-time) ----
  float HFd0[8], HFd1[8];
  {
    float Hs0[8], Hs1[8];
#pragma unroll
    for (int i = 0; i < 8; ++i) { Hs0[i] = Hm[i]; Hs1[i] = Hm[8 + i]; }
    float hfc0 = 0.f, hfc1 = 0.f;   // (H F)[i][r]
#pragma unroll
    for (int jj = 0; jj < 8; ++jj) {
      const float fc = Fm[(jj << 3) | r];   // F[jj][r]
      hfc0 = fmaf(Hs0[jj], fc, hfc0);
      hfc1 = fmaf(Hs1[jj], fc, hfc1);
    }
    gather8(hfc0, HFd0);
    gather8(hfc1, HFd1);
  }

  // ---- per-group state: lane r holds m[r] and P~[d] = P[r][r^d] ----
  float m = m0[(size_t)g * 8 + r];
  float P[8];
#pragma unroll
  for (int d = 0; d < 8; ++d)
    P[d] = P0[(size_t)g * 64 + (r << 3) + (r ^ d)];

  const float* xg = x + (size_t)g * NT * 2;
  float* mo = out + (size_t)g * NT * 2;
  float* co = out + (size_t)NG * NT * 2 + (size_t)g * NT * 4;

  // ---- init measurement mean mm = H m (one-time gather) ----
  float mm0, mm1;
  {
    float MU[8];
    gather8(m, MU);
    float a = Hd0[0] * MU[0], b = Hd1[0] * MU[0];
#pragma unroll
    for (int e = 1; e < 8; ++e) {
      a = fmaf(Hd0[e], MU[e], a);
      b = fmaf(Hd1[e], MU[e], b);
    }
    mm0 = a; mm1 = b;
  }

  float kt0 = 0.f, kt1 = 0.f, s00 = 0.f, s01 = 0.f, s11 = 0.f;

  // ---- x double-buffer: 4-step batches ----
  float4 xa = *reinterpret_cast<const float4*>(xg);
  float4 xb = *reinterpret_cast<const float4*>(xg + 4);
  float4 na = *reinterpret_cast<const float4*>(xg + 8);
  float4 nb = *reinterpret_cast<const float4*>(xg + 12);

  int tb = 0;
  bool wfrozen = false;

  // ================= Phase 1: Riccati (until wave-uniform freeze) ==========
#pragma unroll 1
  for (; tb < NT && !wfrozen; tb += 4) {
    float dmax = 0.f;
#pragma unroll
    for (int j = 0; j < 4; ++j) {
      const int t = tb + j;
      const float x0 = (j == 0) ? xa.x : (j == 1) ? xa.z : (j == 2) ? xb.x : xb.z;
      const float x1 = (j == 0) ? xa.y : (j == 1) ? xa.w : (j == 2) ? xb.y : xb.w;

      // ---- hp_i = (H P)[i][r] via P symmetry (local) ----
      float hp0 = Hd0[0] * P[0];
      float hp1 = Hd1[0] * P[0];
#pragma unroll
      for (int c = 1; c < 8; ++c) {
        hp0 = fmaf(Hd0[c], P[c], hp0);
        hp1 = fmaf(Hd1[c], P[c], hp1);
      }

      // ---- allgather hp on LDS pipe (14 swizzle, issued together) ----
      float G0[8], G1[8];
      gatherS(hp0, G0);
      gatherS(hp1, G1);

      // ---- shadow work while swizzles fly: mm store + innovation ----
      if (r == 0) *reinterpret_cast<float2*>(mo + 2 * t) = make_float2(mm0, mm1);
      const float y0 = x0 - mm0, y1 = x1 - mm1;

      // ---- S = HP H^T + R  (local redundant dots) ----
      float sa = G0[0] * Hd0[0], sb = G0[0] * Hd1[0], sc = G1[0] * Hd1[0];
#pragma unroll
      for (int e = 1; e < 8; ++e) {
        sa = fmaf(G0[e], Hd0[e], sa);
        sb = fmaf(G0[e], Hd1[e], sb);
        sc = fmaf(G1[e], Hd1[e], sc);
      }
      s00 = R00 + sa; s01 = R01 + sb; s11 = R11 + sc;

      // ---- 2x2 inverse, gain column r ----
      const float det  = fmaf(s00, s11, -(s01 * s01));
      const float rdet = 1.0f / det;
      const float i00 = s11 * rdet, i01 = -s01 * rdet, i11 = s00 * rdet;
      kt0 = i00 * hp0 + i01 * hp1;
      kt1 = i01 * hp0 + i11 * hp1;

      // ---- mu early; issue its gather (LDS pipe) under the Ct product ----
      const float mu = fmaf(kt0, y0, fmaf(kt1, y1, m));
      float MU[8];
      gatherS(mu, MU);

      if (r == 1) *reinterpret_cast<float4*>(co + 4 * t) = make_float4(s00, s01, s01, s11);

      // ---- Pu~[d] = P~[d] - kt0*G0[d] - kt1*G1[d] ----
      float Pu[8];
#pragma unroll
      for (int d = 0; d < 8; ++d)
        Pu[d] = fmaf(-kt0, G0[d], fmaf(-kt1, G1[d], P[d]));

      // ---- C = F Pu (columns, local): Ct[e] = C[r^e][r] ----
      float Ct[8];
#pragma unroll
      for (int e = 0; e < 8; ++e) {
        float acc = Fde[e][0] * Pu[0];
#pragma unroll
        for (int d = 1; d < 8; ++d) acc = fmaf(Fde[e][d], Pu[d], acc);
        Ct[e] = acc;
      }

      // ---- transpose on LDS pipe: Crow[e] = C[r][r^e] = SWZ(Ct[e], e) ----
      float Crow[8];
      Crow[0] = Ct[0];
      Crow[1] = SWZ(Ct[1], 1); Crow[2] = SWZ(Ct[2], 2);
      Crow[3] = SWZ(Ct[3], 3); Crow[4] = SWZ(Ct[4], 4);
      Crow[5] = SWZ(Ct[5], 5); Crow[6] = SWZ(Ct[6], 6);
      Crow[7] = SWZ(Ct[7], 7);

      // ---- partial Pn with e=0 (no swizzle dependency) fills latency ----
      float Pn[8];
#pragma unroll
      for (int d = 0; d < 8; ++d) Pn[d] = fmaf(Fde[d][0], Crow[0], Qt[d]);
#pragma unroll
      for (int d = 0; d < 8; ++d) {
        float acc = Pn[d];
#pragma unroll
        for (int e = 1; e < 8; ++e) acc = fmaf(Fde[d][e], Crow[e], acc);
        Pn[d] = acc;
      }

      // ---- mean + measurement-mean recursion (MU ready by now) ----
      float ma = Frt[0] * MU[0], h0 = HFd0[0] * MU[0], h1 = HFd1[0] * MU[0];
#pragma unroll
      for (int e = 1; e < 8; ++e) {
        ma = fmaf(Frt[e],  MU[e], ma);
        h0 = fmaf(HFd0[e], MU[e], h0);
        h1 = fmaf(HFd1[e], MU[e], h1);
      }
      m = ma; mm0 = h0; mm1 = h1;

      // ---- freeze metric (every 4th step); __all covers all lanes ----
      if (j == 3) {
        float dm = 0.f;
#pragma unroll
        for (int c = 0; c < 8; ++c) dm = fmaxf(dm, fabsf(Pn[c] - P[c]));
        dmax = dm;
      }
#pragma unroll
      for (int c = 0; c < 8; ++c) P[c] = Pn[c];
    }
    xa = na; xb = nb;
    int tf = tb + 8; if (tf > NT - 4) tf = NT - 4;
    na = *reinterpret_cast<const float4*>(xg + 2 * tf);
    nb = *reinterpret_cast<const float4*>(xg + 2 * tf + 4);
    wfrozen = (__all(dmax < FREEZE_EPS) != 0);
  }

  // ================= Phase 2: steady-state linear filter ====================
  if (tb < NT) {
    // constant covariance blast: lane-strided float4
    const float4 cv = make_float4(s00, s01, s01, s11);
#pragma unroll 1
    for (int k2 = tb + r; k2 < NT; k2 += 8)
      *reinterpret_cast<float4*>(co + 4 * k2) = cv;

#pragma unroll 1
    for (; tb < NT; tb += 4) {
      float2 b0, b1, b2, b3;
#pragma unroll
      for (int j = 0; j < 4; ++j) {
        const float x0 = (j == 0) ? xa.x : (j == 1) ? xa.z : (j == 2) ? xb.x : xb.z;
        const float x1 = (j == 0) ? xa.y : (j == 1) ? xa.w : (j == 2) ? xb.y : xb.w;
        if (j == 0) b0 = make_float2(mm0, mm1);
        else if (j == 1) b1 = make_float2(mm0, mm1);
        else if (j == 2) b2 = make_float2(mm0, mm1);
        else b3 = make_float2(mm0, mm1);
        const float y0 = x0 - mm0, y1 = x1 - mm1;
        const float mu = fmaf(kt0, y0, fmaf(kt1, y1, m));
        float MU[8];
        gather8(mu, MU);   // DPP: short serial chain, no LDS round-trip
        float ma = Frt[0] * MU[0], h0 = HFd0[0] * MU[0], h1 = HFd1[0] * MU[0];
#pragma unroll
        for (int e = 1; e < 8; ++e) {
          ma = fmaf(Frt[e],  MU[e], ma);
          h0 = fmaf(HFd0[e], MU[e], h0);
          h1 = fmaf(HFd1[e], MU[e], h1);
        }
        m = ma; mm0 = h0; mm1 = h1;
      }
      if (r == 0) {
        *reinterpret_cast<float4*>(mo + 2 * tb)     = make_float4(b0.x, b0.y, b1.x, b1.y);
        *reinterpret_cast<float4*>(mo + 2 * tb + 4) = make_float4(b2.x, b2.y, b3.x, b3.y);
      }
      xa = na; xb = nb;
      int tf = tb + 8; if (tf > NT - 4) tf = NT - 4;
      na = *reinterpret_cast<const float4*>(xg + 2 * tf);
      nb = *reinterpret_cast<const float4*>(xg + 2 * tf + 4);
    }
  }
}

extern "C" void kernel_launch(void* const* d_in, const int* in_sizes, int n_in,
                              void* d_out, int out_size, void* d_ws, size_t ws_size,
                              hipStream_t stream) {
  const float* x  = (const float*)d_in[0];
  const float* m0 = (const float*)d_in[1];
  const float* P0 = (const float*)d_in[2];
  const float* F  = (const float*)d_in[3];
  const float* Q  = (const float*)d_in[4];
  const float* H  = (const float*)d_in[5];
  const float* R  = (const float*)d_in[6];
  float* out = (float*)d_out;

  dim3 grid(NG * 8 / 256), block(256);
  hipLaunchKernelGGL(kf_kernel, grid, block, 0, stream,
                     x, m0, P0, F, Q, H, R, out);
}

// Round 12
// 162.863 us; speedup vs baseline: 1.9763x; 1.0043x over previous
//
#include <hip/hip_runtime.h>

#define NG 16384
#define NT 200
#define EPS_K 5e-5f
#define EPS_S 5e-4f

// DPP cross-lane (VALU pipe) — used where rare / latency-critical
#define DPPF(v, ctrl) __int_as_float(__builtin_amdgcn_update_dpp( \
    0, __float_as_int(v), (ctrl), 0xF, 0xF, true))
#define QP1(v) DPPF(v, 0xB1)   // src lane ^ 1
#define QP2(v) DPPF(v, 0x4E)   // src lane ^ 2
#define RHM(v) DPPF(v, 0x141)  // src lane ^ 7
// LDS-pipe xor-shuffle: lane r reads lane r^e (BitMode: and=0x1f, or=0, xor=e)
#define SWZ(v, e) __int_as_float(__builtin_amdgcn_ds_swizzle( \
    __float_as_int(v), ((e) << 10) | 0x1F))

// xor-allgather via DPP (7 ops) — init / phase-2 (short serial chain)
__device__ __forceinline__ void gather8(float v, float* __restrict__ o) {
  o[0] = v;
  o[1] = QP1(v);
  o[2] = QP2(v);
  o[3] = QP2(o[1]);
  o[7] = RHM(v);
  o[6] = RHM(o[1]);
  o[5] = RHM(o[2]);
  o[4] = RHM(o[3]);
}
// xor-allgather via ds_swizzle (LDS pipe, all independent)
__device__ __forceinline__ void gatherS(float v, float* __restrict__ o) {
  o[0] = v;
  o[1] = SWZ(v, 1); o[2] = SWZ(v, 2); o[3] = SWZ(v, 3); o[4] = SWZ(v, 4);
  o[5] = SWZ(v, 5); o[6] = SWZ(v, 6); o[7] = SWZ(v, 7);
}

__global__ __launch_bounds__(256, 2)
void kf_kernel(const float* __restrict__ x,
               const float* __restrict__ m0,
               const float* __restrict__ P0,
               const float* __restrict__ Fm,
               const float* __restrict__ Qm,
               const float* __restrict__ Hm,
               const float* __restrict__ Rm,
               float* __restrict__ out) {
  const int tid = threadIdx.x;
  const int r   = tid & 7;
  const int g   = blockIdx.x * 32 + (tid >> 3);

  // ---- per-lane xor-indexed parameter tables ----
  float Frt[8], Qt[8], Hd0[8], Hd1[8];
#pragma unroll
  for (int c = 0; c < 8; ++c) {
    Frt[c] = Fm[(r << 3) | (r ^ c)];   // F[r][r^c]
    Qt[c]  = Qm[(r << 3) | (r ^ c)];   // Q[r][r^c]
    Hd0[c] = Hm[r ^ c];                // H[0][r^c]
    Hd1[c] = Hm[8 + (r ^ c)];          // H[1][r^c]
  }
  const float R00 = Rm[0], R01 = Rm[1], R11 = Rm[3];

  // ---- Fde[dl][c] = F[r^dl][r^c] via DPP chains (one-time) ----
  float Fde[8][8];
  {
    float t1[8], t2[8], t3[8], tt[8];
#pragma unroll
    for (int c = 0; c < 8; ++c) Fde[0][c] = Frt[c];
#pragma unroll
    for (int c = 0; c < 8; ++c) t1[c] = QP1(Frt[c]);
#pragma unroll
    for (int c = 0; c < 8; ++c) Fde[1][c] = t1[1 ^ c];
#pragma unroll
    for (int c = 0; c < 8; ++c) t2[c] = QP2(Frt[c]);
#pragma unroll
    for (int c = 0; c < 8; ++c) Fde[2][c] = t2[2 ^ c];
#pragma unroll
    for (int c = 0; c < 8; ++c) t3[c] = QP2(t1[c]);
#pragma unroll
    for (int c = 0; c < 8; ++c) Fde[3][c] = t3[3 ^ c];
#pragma unroll
    for (int c = 0; c < 8; ++c) tt[c] = RHM(Frt[c]);
#pragma unroll
    for (int c = 0; c < 8; ++c) Fde[7][c] = tt[7 ^ c];
#pragma unroll
    for (int c = 0; c < 8; ++c) tt[c] = RHM(t1[c]);
#pragma unroll
    for (int c = 0; c < 8; ++c) Fde[6][c] = tt[6 ^ c];
#pragma unroll
    for (int c = 0; c < 8; ++c) tt[c] = RHM(t2[c]);
#pragma unroll
    for (int c = 0; c < 8; ++c) Fde[5][c] = tt[5 ^ c];
#pragma unroll
    for (int c = 0; c < 8; ++c) tt[c] = RHM(t3[c]);
#pragma unroll
    for (int c = 0; c < 8; ++c) Fde[4][c] = tt[4 ^ c];
  }

  // ---- HFd tables: HFd_i[e] = (H F)[i][r^e]  (one-time) ----
  float HFd0[8], HFd1[8];
  {
    float Hs0[8], Hs1[8];
#pragma unroll
    for (int i = 0; i < 8; ++i) { Hs0[i] = Hm[i]; Hs1[i] = Hm[8 + i]; }
    float hfc0 = 0.f, hfc1 = 0.f;   // (H F)[i][r]
#pragma unroll
    for (int jj = 0; jj < 8; ++jj) {
      const float fc = Fm[(jj << 3) | r];   // F[jj][r]
      hfc0 = fmaf(Hs0[jj], fc, hfc0);
      hfc1 = fmaf(Hs1[jj], fc, hfc1);
    }
    gather8(hfc0, HFd0);
    gather8(hfc1, HFd1);
  }

  // ---- per-group state: lane r holds m[r] and P~[d] = P[r][r^d] ----
  float m = m0[(size_t)g * 8 + r];
  float P[8];
#pragma unroll
  for (int d = 0; d < 8; ++d)
    P[d] = P0[(size_t)g * 64 + (r << 3) + (r ^ d)];

  const float* xg = x + (size_t)g * NT * 2;
  float* mo = out + (size_t)g * NT * 2;
  float* co = out + (size_t)NG * NT * 2 + (size_t)g * NT * 4;

  // ---- init measurement mean mm = H m (one-time gather) ----
  float mm0, mm1;
  {
    float MU[8];
    gather8(m, MU);
    float a = Hd0[0] * MU[0], b = Hd1[0] * MU[0];
#pragma unroll
    for (int e = 1; e < 8; ++e) {
      a = fmaf(Hd0[e], MU[e], a);
      b = fmaf(Hd1[e], MU[e], b);
    }
    mm0 = a; mm1 = b;
  }

  float kt0 = 0.f, kt1 = 0.f, s00 = 0.f, s01 = 0.f, s11 = 0.f;
  // previous-check snapshots for the output-convergence freeze
  float kt0p = 1e30f, kt1p = 1e30f, s00p = 1e30f, s01p = 1e30f, s11p = 1e30f;

  // ---- x double-buffer: 4-step batches ----
  float4 xa = *reinterpret_cast<const float4*>(xg);
  float4 xb = *reinterpret_cast<const float4*>(xg + 4);
  float4 na = *reinterpret_cast<const float4*>(xg + 8);
  float4 nb = *reinterpret_cast<const float4*>(xg + 12);

  int tb = 0;
  bool wfrozen = false;

  // ================= Phase 1: Riccati (until wave-uniform K/S freeze) ======
#pragma unroll 1
  for (; tb < NT && !wfrozen; tb += 4) {
    float dmax = 0.f;
#pragma unroll
    for (int j = 0; j < 4; ++j) {
      const int t = tb + j;
      const float x0 = (j == 0) ? xa.x : (j == 1) ? xa.z : (j == 2) ? xb.x : xb.z;
      const float x1 = (j == 0) ? xa.y : (j == 1) ? xa.w : (j == 2) ? xb.y : xb.w;

      // ---- hp_i = (H P)[i][r] via P symmetry (local) ----
      float hp0 = Hd0[0] * P[0];
      float hp1 = Hd1[0] * P[0];
#pragma unroll
      for (int c = 1; c < 8; ++c) {
        hp0 = fmaf(Hd0[c], P[c], hp0);
        hp1 = fmaf(Hd1[c], P[c], hp1);
      }

      // ---- allgather hp on LDS pipe (14 swizzle, independent) ----
      float G0[8], G1[8];
      gatherS(hp0, G0);
      gatherS(hp1, G1);

      // ---- shadow work while swizzles fly ----
      if (r == 0) *reinterpret_cast<float2*>(mo + 2 * t) = make_float2(mm0, mm1);
      const float y0 = x0 - mm0, y1 = x1 - mm1;

      // ---- S = HP H^T + R  (local redundant dots on gathered G) ----
      float sa = G0[0] * Hd0[0], sb = G0[0] * Hd1[0], sc = G1[0] * Hd1[0];
#pragma unroll
      for (int e = 1; e < 8; ++e) {
        sa = fmaf(G0[e], Hd0[e], sa);
        sb = fmaf(G0[e], Hd1[e], sb);
        sc = fmaf(G1[e], Hd1[e], sc);
      }
      s00 = R00 + sa; s01 = R01 + sb; s11 = R11 + sc;

      // ---- gain column r: direct 2x2 solve ----
      const float det  = fmaf(s00, s11, -(s01 * s01));
      const float rdet = 1.0f / det;
      kt0 = fmaf(s11, hp0, -(s01 * hp1)) * rdet;
      kt1 = fmaf(s00, hp1, -(s01 * hp0)) * rdet;

      // ---- mu early; its gather flies under the Ct product ----
      const float mu = fmaf(kt0, y0, fmaf(kt1, y1, m));
      float MU[8];
      gatherS(mu, MU);

      if (r == 1) *reinterpret_cast<float4*>(co + 4 * t) = make_float4(s00, s01, s01, s11);

      // ---- Pu~[d] = P~[d] - kt0*G0[d] - kt1*G1[d] ----
      float Pu[8];
#pragma unroll
      for (int d = 0; d < 8; ++d)
        Pu[d] = fmaf(-kt0, G0[d], fmaf(-kt1, G1[d], P[d]));

      // ---- C = F Pu (columns, local): Ct[e] = C[r^e][r] ----
      float Ct[8];
#pragma unroll
      for (int e = 0; e < 8; ++e) {
        float acc = Fde[e][0] * Pu[0];
#pragma unroll
        for (int d = 1; d < 8; ++d) acc = fmaf(Fde[e][d], Pu[d], acc);
        Ct[e] = acc;
      }

      // ---- transpose on LDS pipe: Crow[e] = C[r][r^e] = SWZ(Ct[e], e) ----
      float Crow[8];
      Crow[0] = Ct[0];
      Crow[1] = SWZ(Ct[1], 1); Crow[2] = SWZ(Ct[2], 2);
      Crow[3] = SWZ(Ct[3], 3); Crow[4] = SWZ(Ct[4], 4);
      Crow[5] = SWZ(Ct[5], 5); Crow[6] = SWZ(Ct[6], 6);
      Crow[7] = SWZ(Ct[7], 7);

      // ---- P~[d] = Qt[d] + sum_e Fde[d][e] * Crow[e]  (in place; P dead) ----
#pragma unroll
      for (int d = 0; d < 8; ++d) {
        float acc = fmaf(Fde[d][0], Crow[0], Qt[d]);
#pragma unroll
        for (int e = 1; e < 8; ++e) acc = fmaf(Fde[d][e], Crow[e], acc);
        P[d] = acc;
      }

      // ---- mean + measurement-mean recursion (MU ready by now) ----
      float ma = Frt[0] * MU[0], h0 = HFd0[0] * MU[0], h1 = HFd1[0] * MU[0];
#pragma unroll
      for (int e = 1; e < 8; ++e) {
        ma = fmaf(Frt[e],  MU[e], ma);
        h0 = fmaf(HFd0[e], MU[e], h0);
        h1 = fmaf(HFd1[e], MU[e], h1);
      }
      m = ma; mm0 = h0; mm1 = h1;

      // ---- output-convergence freeze metric (every 4th step) ----
      if (j == 3) {
        float dk = fmaxf(fabsf(kt0 - kt0p), fabsf(kt1 - kt1p));
        float ds = fmaxf(fabsf(s00 - s00p),
                         fmaxf(fabsf(s01 - s01p), fabsf(s11 - s11p)));
        dmax = fmaxf(dk, ds * (EPS_K / EPS_S));
        kt0p = kt0; kt1p = kt1; s00p = s00; s01p = s01; s11p = s11;
      }
    }
    xa = na; xb = nb;
    int tf = tb + 8; if (tf > NT - 4) tf = NT - 4;
    na = *reinterpret_cast<const float4*>(xg + 2 * tf);
    nb = *reinterpret_cast<const float4*>(xg + 2 * tf + 4);
    wfrozen = (__all(dmax < EPS_K) != 0);
  }

  // ================= Phase 2: steady-state linear filter ====================
  if (tb < NT) {
    // constant covariance blast: lane-strided float4
    const float4 cv = make_float4(s00, s01, s01, s11);
#pragma unroll 1
    for (int k2 = tb + r; k2 < NT; k2 += 8)
      *reinterpret_cast<float4*>(co + 4 * k2) = cv;

#pragma unroll 1
    for (; tb < NT; tb += 4) {
      float2 b0, b1, b2, b3;
#pragma unroll
      for (int j = 0; j < 4; ++j) {
        const float x0 = (j == 0) ? xa.x : (j == 1) ? xa.z : (j == 2) ? xb.x : xb.z;
        const float x1 = (j == 0) ? xa.y : (j == 1) ? xa.w : (j == 2) ? xb.y : xb.w;
        if (j == 0) b0 = make_float2(mm0, mm1);
        else if (j == 1) b1 = make_float2(mm0, mm1);
        else if (j == 2) b2 = make_float2(mm0, mm1);
        else b3 = make_float2(mm0, mm1);
        const float y0 = x0 - mm0, y1 = x1 - mm1;
        const float mu = fmaf(kt0, y0, fmaf(kt1, y1, m));
        float MU[8];
        gather8(mu, MU);   // DPP: short serial chain, no LDS round-trip
        float ma = Frt[0] * MU[0], h0 = HFd0[0] * MU[0], h1 = HFd1[0] * MU[0];
#pragma unroll
        for (int e = 1; e < 8; ++e) {
          ma = fmaf(Frt[e],  MU[e], ma);
          h0 = fmaf(HFd0[e], MU[e], h0);
          h1 = fmaf(HFd1[e], MU[e], h1);
        }
        m = ma; mm0 = h0; mm1 = h1;
      }
      if (r == 0) {
        *reinterpret_cast<float4*>(mo + 2 * tb)     = make_float4(b0.x, b0.y, b1.x, b1.y);
        *reinterpret_cast<float4*>(mo + 2 * tb + 4) = make_float4(b2.x, b2.y, b3.x, b3.y);
      }
      xa = na; xb = nb;
      int tf = tb + 8; if (tf > NT - 4) tf = NT - 4;
      na = *reinterpret_cast<const float4*>(xg + 2 * tf);
      nb = *reinterpret_cast<const float4*>(xg + 2 * tf + 4);
    }
  }
}

extern "C" void kernel_launch(void* const* d_in, const int* in_sizes, int n_in,
                              void* d_out, int out_size, void* d_ws, size_t ws_size,
                              hipStream_t stream) {
  const float* x  = (const float*)d_in[0];
  const float* m0 = (const float*)d_in[1];
  const float* P0 = (const float*)d_in[2];
  const float* F  = (const float*)d_in[3];
  const float* Q  = (const float*)d_in[4];
  const float* H  = (const float*)d_in[5];
  const float* R  = (const float*)d_in[6];
  float* out = (float*)d_out;

  dim3 grid(NG * 8 / 256), block(256);
  hipLaunchKernelGGL(kf_kernel, grid, block, 0, stream,
                     x, m0, P0, F, Q, H, R, out);
}

// Round 13
// 160.705 us; speedup vs baseline: 2.0028x; 1.0134x over previous
//
#include <hip/hip_runtime.h>

#define NG 16384
#define NT 200

// DPP cross-lane (VALU pipe)
#define DPPF(v, ctrl) __int_as_float(__builtin_amdgcn_update_dpp( \
    0, __float_as_int(v), (ctrl), 0xF, 0xF, true))
#define QP1(v) DPPF(v, 0xB1)   // src lane ^ 1
#define QP2(v) DPPF(v, 0x4E)   // src lane ^ 2
#define RHM(v) DPPF(v, 0x141)  // src lane ^ 7
// LDS-pipe xor-shuffle: lane r reads lane r^e
#define SWZ(v, e) __int_as_float(__builtin_amdgcn_ds_swizzle( \
    __float_as_int(v), ((e) << 10) | 0x1F))
// pin a value into a VGPR, opaque to rematerialization
#define PIN(v) asm volatile("" : "+v"(v))

// xor-allgather via DPP (7 ops) — init only
__device__ __forceinline__ void gather8(float v, float* __restrict__ o) {
  o[0] = v;
  o[1] = QP1(v);
  o[2] = QP2(v);
  o[3] = QP2(o[1]);
  o[7] = RHM(v);
  o[6] = RHM(o[1]);
  o[5] = RHM(o[2]);
  o[4] = RHM(o[3]);
}
// xor-allgather via ds_swizzle (LDS pipe, all independent)
__device__ __forceinline__ void gatherS(float v, float* __restrict__ o) {
  o[0] = v;
  o[1] = SWZ(v, 1); o[2] = SWZ(v, 2); o[3] = SWZ(v, 3); o[4] = SWZ(v, 4);
  o[5] = SWZ(v, 5); o[6] = SWZ(v, 6); o[7] = SWZ(v, 7);
}

__global__ __launch_bounds__(256, 1)
void kf_kernel(const float* __restrict__ x,
               const float* __restrict__ m0,
               const float* __restrict__ P0,
               const float* __restrict__ Fm,
               const float* __restrict__ Qm,
               const float* __restrict__ Hm,
               const float* __restrict__ Rm,
               float* __restrict__ out) {
  const int tid = threadIdx.x;
  const int r   = tid & 7;
  const int g   = blockIdx.x * 32 + (tid >> 3);

  // ---- per-lane xor-indexed parameter tables ----
  float Frt[8], Qt[8], Hd0[8], Hd1[8];
#pragma unroll
  for (int c = 0; c < 8; ++c) {
    Frt[c] = Fm[(r << 3) | (r ^ c)];   // F[r][r^c]
    Qt[c]  = Qm[(r << 3) | (r ^ c)];   // Q[r][r^c]
    Hd0[c] = Hm[r ^ c];                // H[0][r^c]
    Hd1[c] = Hm[8 + (r ^ c)];          // H[1][r^c]
  }
  const float R00 = Rm[0], R01 = Rm[1], R11 = Rm[3];

  // ---- Fde[dl][c] = F[r^dl][r^c] via DPP chains (one-time) ----
  float Fde[8][8];
  {
    float t1[8], t2[8], t3[8], tt[8];
#pragma unroll
    for (int c = 0; c < 8; ++c) Fde[0][c] = Frt[c];
#pragma unroll
    for (int c = 0; c < 8; ++c) t1[c] = QP1(Frt[c]);
#pragma unroll
    for (int c = 0; c < 8; ++c) Fde[1][c] = t1[1 ^ c];
#pragma unroll
    for (int c = 0; c < 8; ++c) t2[c] = QP2(Frt[c]);
#pragma unroll
    for (int c = 0; c < 8; ++c) Fde[2][c] = t2[2 ^ c];
#pragma unroll
    for (int c = 0; c < 8; ++c) t3[c] = QP2(t1[c]);
#pragma unroll
    for (int c = 0; c < 8; ++c) Fde[3][c] = t3[3 ^ c];
#pragma unroll
    for (int c = 0; c < 8; ++c) tt[c] = RHM(Frt[c]);
#pragma unroll
    for (int c = 0; c < 8; ++c) Fde[7][c] = tt[7 ^ c];
#pragma unroll
    for (int c = 0; c < 8; ++c) tt[c] = RHM(t1[c]);
#pragma unroll
    for (int c = 0; c < 8; ++c) Fde[6][c] = tt[6 ^ c];
#pragma unroll
    for (int c = 0; c < 8; ++c) tt[c] = RHM(t2[c]);
#pragma unroll
    for (int c = 0; c < 8; ++c) Fde[5][c] = tt[5 ^ c];
#pragma unroll
    for (int c = 0; c < 8; ++c) tt[c] = RHM(t3[c]);
#pragma unroll
    for (int c = 0; c < 8; ++c) Fde[4][c] = tt[4 ^ c];
  }

  // ---- HFd tables: HFd_i[e] = (H F)[i][r^e]  (one-time) ----
  float HFd0[8], HFd1[8];
  {
    float Hs0[8], Hs1[8];
#pragma unroll
    for (int i = 0; i < 8; ++i) { Hs0[i] = Hm[i]; Hs1[i] = Hm[8 + i]; }
    float hfc0 = 0.f, hfc1 = 0.f;   // (H F)[i][r]
#pragma unroll
    for (int jj = 0; jj < 8; ++jj) {
      const float fc = Fm[(jj << 3) | r];   // F[jj][r]
      hfc0 = fmaf(Hs0[jj], fc, hfc0);
      hfc1 = fmaf(Hs1[jj], fc, hfc1);
    }
    gather8(hfc0, HFd0);
    gather8(hfc1, HFd1);
  }

  // ---- pin all loop-invariant tables into VGPRs (defeat remat) ----
#pragma unroll
  for (int e = 0; e < 8; ++e)
#pragma unroll
    for (int c = 0; c < 8; ++c) PIN(Fde[e][c]);
#pragma unroll
  for (int c = 0; c < 8; ++c) {
    PIN(Frt[c]); PIN(Qt[c]); PIN(Hd0[c]); PIN(Hd1[c]);
    PIN(HFd0[c]); PIN(HFd1[c]);
  }

  // ---- per-group state: lane r holds m[r] and P~[d] = P[r][r^d] ----
  float m = m0[(size_t)g * 8 + r];
  float P[8];
#pragma unroll
  for (int d = 0; d < 8; ++d)
    P[d] = P0[(size_t)g * 64 + (r << 3) + (r ^ d)];

  const float* xg = x + (size_t)g * NT * 2;
  float* mo = out + (size_t)g * NT * 2;
  float* co = out + (size_t)NG * NT * 2 + (size_t)g * NT * 4;

  // ---- init measurement mean mm = H m (one-time gather) ----
  float mm0, mm1;
  {
    float MU[8];
    gather8(m, MU);
    float a = Hd0[0] * MU[0], b = Hd1[0] * MU[0];
#pragma unroll
    for (int e = 1; e < 8; ++e) {
      a = fmaf(Hd0[e], MU[e], a);
      b = fmaf(Hd1[e], MU[e], b);
    }
    mm0 = a; mm1 = b;
  }

  // ---- x double-buffer: 4-step batches ----
  float4 xa = *reinterpret_cast<const float4*>(xg);
  float4 xb = *reinterpret_cast<const float4*>(xg + 4);
  float4 na = *reinterpret_cast<const float4*>(xg + 8);
  float4 nb = *reinterpret_cast<const float4*>(xg + 12);

  // ================= full Riccati, all NT steps ==========================
#pragma unroll 1
  for (int tb = 0; tb < NT; tb += 4) {
#pragma unroll
    for (int j = 0; j < 4; ++j) {
      const int t = tb + j;
      const float x0 = (j == 0) ? xa.x : (j == 1) ? xa.z : (j == 2) ? xb.x : xb.z;
      const float x1 = (j == 0) ? xa.y : (j == 1) ? xa.w : (j == 2) ? xb.y : xb.w;

      // ---- hp_i = (H P)[i][r] via P symmetry (local) ----
      float hp0 = Hd0[0] * P[0];
      float hp1 = Hd1[0] * P[0];
#pragma unroll
      for (int c = 1; c < 8; ++c) {
        hp0 = fmaf(Hd0[c], P[c], hp0);
        hp1 = fmaf(Hd1[c], P[c], hp1);
      }

      // ---- allgather hp on LDS pipe (14 swizzle, independent) ----
      float G0[8], G1[8];
      gatherS(hp0, G0);
      gatherS(hp1, G1);

      // ---- shadow work while swizzles fly ----
      if (r == 0) *reinterpret_cast<float2*>(mo + 2 * t) = make_float2(mm0, mm1);
      const float y0 = x0 - mm0, y1 = x1 - mm1;

      // ---- S = HP H^T + R  (local redundant dots on gathered G) ----
      float sa = G0[0] * Hd0[0], sb = G0[0] * Hd1[0], sc = G1[0] * Hd1[0];
#pragma unroll
      for (int e = 1; e < 8; ++e) {
        sa = fmaf(G0[e], Hd0[e], sa);
        sb = fmaf(G0[e], Hd1[e], sb);
        sc = fmaf(G1[e], Hd1[e], sc);
      }
      const float s00 = R00 + sa, s01 = R01 + sb, s11 = R11 + sc;

      // ---- gain column r: direct 2x2 solve ----
      const float det  = fmaf(s00, s11, -(s01 * s01));
      const float rdet = 1.0f / det;
      const float kt0 = fmaf(s11, hp0, -(s01 * hp1)) * rdet;
      const float kt1 = fmaf(s00, hp1, -(s01 * hp0)) * rdet;

      // ---- mu early; its gather flies under the Ct product ----
      const float mu = fmaf(kt0, y0, fmaf(kt1, y1, m));
      float MU[8];
      gatherS(mu, MU);

      if (r == 1) *reinterpret_cast<float4*>(co + 4 * t) = make_float4(s00, s01, s01, s11);

      // ---- Pu~[d] = P~[d] - kt0*G0[d] - kt1*G1[d] ----
      float Pu[8];
#pragma unroll
      for (int d = 0; d < 8; ++d)
        Pu[d] = fmaf(-kt0, G0[d], fmaf(-kt1, G1[d], P[d]));

      // ---- C = F Pu (columns, local): Ct[e] = C[r^e][r] ----
      float Ct[8];
#pragma unroll
      for (int e = 0; e < 8; ++e) {
        float acc = Fde[e][0] * Pu[0];
#pragma unroll
        for (int d = 1; d < 8; ++d) acc = fmaf(Fde[e][d], Pu[d], acc);
        Ct[e] = acc;
      }

      // ---- transpose on LDS pipe: Crow[e] = C[r][r^e] = SWZ(Ct[e], e) ----
      float Crow[8];
      Crow[0] = Ct[0];
      Crow[1] = SWZ(Ct[1], 1); Crow[2] = SWZ(Ct[2], 2);
      Crow[3] = SWZ(Ct[3], 3); Crow[4] = SWZ(Ct[4], 4);
      Crow[5] = SWZ(Ct[5], 5); Crow[6] = SWZ(Ct[6], 6);
      Crow[7] = SWZ(Ct[7], 7);

      // ---- P~[d] = Qt[d] + sum_e Fde[d][e] * Crow[e]  (in place) ----
#pragma unroll
      for (int d = 0; d < 8; ++d) {
        float acc = fmaf(Fde[d][0], Crow[0], Qt[d]);
#pragma unroll
        for (int e = 1; e < 8; ++e) acc = fmaf(Fde[d][e], Crow[e], acc);
        P[d] = acc;
      }

      // ---- mean + measurement-mean recursion (MU ready by now) ----
      float ma = Frt[0] * MU[0], h0 = HFd0[0] * MU[0], h1 = HFd1[0] * MU[0];
#pragma unroll
      for (int e = 1; e < 8; ++e) {
        ma = fmaf(Frt[e],  MU[e], ma);
        h0 = fmaf(HFd0[e], MU[e], h0);
        h1 = fmaf(HFd1[e], MU[e], h1);
      }
      m = ma; mm0 = h0; mm1 = h1;
    }
    xa = na; xb = nb;
    int tf = tb + 8; if (tf > NT - 4) tf = NT - 4;
    na = *reinterpret_cast<const float4*>(xg + 2 * tf);
    nb = *reinterpret_cast<const float4*>(xg + 2 * tf + 4);
  }
}

extern "C" void kernel_launch(void* const* d_in, const int* in_sizes, int n_in,
                              void* d_out, int out_size, void* d_ws, size_t ws_size,
                              hipStream_t stream) {
  const float* x  = (const float*)d_in[0];
  const float* m0 = (const float*)d_in[1];
  const float* P0 = (const float*)d_in[2];
  const float* F  = (const float*)d_in[3];
  const float* Q  = (const float*)d_in[4];
  const float* H  = (const float*)d_in[5];
  const float* R  = (const float*)d_in[6];
  float* out = (float*)d_out;

  dim3 grid(NG * 8 / 256), block(256);
  hipLaunchKernelGGL(kf_kernel, grid, block, 0, stream,
                     x, m0, P0, F, Q, H, R, out);
}